// Round 4
// baseline (260.902 us; speedup 1.0000x reference)
//
#include <hip/hip_runtime.h>

// Sigma-delta integrate-and-fire, validated against a float64 numpy reference
// (round-2 evidence: exact f32-serial replication failed with absmax=1000 ==
// one floor flip; any f32-ordered cumsum flips floors w.h.p. given ~13k
// integer crossings and ~1e-6 f32 random-walk error; threshold 20 is only
// reachable with f64-quality accumulation).
//
// So replicate the f64 reference bit-exactly in the cum/floor path:
//   rd_t = fl64( (f64)relu(x_t) * 0.001 )   (one f64 rounding, = np's rates*DT)
//   s_t  = fl64( s_{t-1} + rd_t )           (serial f64 fold = np.cumsum f64)
//   c_t  = fl64( v0 + s_t ) ; f_t = floor(c_t)   (f64)
//   spike_t = (f32)(f_t - f_{t-1}) * 1000.0f     (vs ref n/0.001_f64: diff ~2e-14)
// fp contract(off) prevents the f64 mul+add fusing into fma (would change
// rounding vs np, which rounds rates*DT before accumulating).
//
// Structure: 16384 independent length-2048 scans = 256 waves of 64 lanes
// (lane = u, coalesced 256B/wave-load), one wave per CU on all 256 CUs.
// Latency hiding is in-wave: 4-deep x 16-element register pipeline => up to
// ~64 loads in flight (16 KB/CU) vs ~9 KB/CU required by Little's law at
// ~900-cycle HBM latency for 10 B/cy/CU. Both streams are touch-once =>
// non-temporal (bypass L2, no read/write cross-thrash).

#define CH 16

__global__ __launch_bounds__(64, 1)
void sdiaf_f64_kernel(const float* __restrict__ x,
                      const float* __restrict__ v0,
                      float* __restrict__ out,
                      int T, int U, int total /* = B*U */) {
#pragma clang fp contract(off)
    const int idx = blockIdx.x * blockDim.x + threadIdx.x;  // flat b*U + u
    if (idx >= total) return;
    const int b = idx / U;
    const int u = idx - b * U;

    const double v0d = (double)v0[idx];     // f32 -> f64 exact
    float fprev32 = (float)floor(v0d);      // small integer, exact in f32
    double s = 0.0;

    const size_t stride = (size_t)U;
    const size_t chstep = (size_t)CH * stride;
    const size_t base = (size_t)b * (size_t)T * stride + (size_t)u;
    const float* __restrict__ xp = x + base;
    float* __restrict__ op = out + base;

    const int nch = T / CH;

    if ((T % (CH * 4)) == 0 && nch >= 8) {
        // --- 4-phase software pipeline, prefetch distance = 4 chunks ---
        float bA[CH], bB[CH], bC[CH], bD[CH];   // static-indexed -> registers

        const float* lpA = xp;                  // load pointers lead by 4 chunks
        const float* lpB = xp + chstep;
        const float* lpC = xp + 2 * chstep;
        const float* lpD = xp + 3 * chstep;
        float* opA = op;

#define LOADCH(buf, lp) do {                                              \
    _Pragma("unroll")                                                     \
    for (int i_ = 0; i_ < CH; ++i_)                                       \
        buf[i_] = __builtin_nontemporal_load(&(lp)[(size_t)i_ * stride]); \
} while (0)

#define PROCCH(buf, o) do {                                               \
    _Pragma("unroll")                                                     \
    for (int i_ = 0; i_ < CH; ++i_) {                                     \
        double rd_ = (double)fmaxf(buf[i_], 0.0f) * 0.001;                \
        s = s + rd_;                       /* serial f64 fold */          \
        double c_ = v0d + s;                                              \
        double f_ = floor(c_);                                            \
        float f32f_ = (float)f_;           /* small int, exact */         \
        __builtin_nontemporal_store((f32f_ - fprev32) * 1000.0f,          \
                                    &(o)[(size_t)i_ * stride]);           \
        fprev32 = f32f_;                                                  \
    }                                                                     \
} while (0)

        LOADCH(bA, lpA); LOADCH(bB, lpB); LOADCH(bC, lpC); LOADCH(bD, lpD);
        lpA += 4 * chstep; lpB += 4 * chstep; lpC += 4 * chstep; lpD += 4 * chstep;

        int ch = 0;
        for (; ch + 4 < nch; ch += 4) {
            PROCCH(bA, opA);                LOADCH(bA, lpA); lpA += 4 * chstep;
            PROCCH(bB, opA + chstep);       LOADCH(bB, lpB); lpB += 4 * chstep;
            PROCCH(bC, opA + 2 * chstep);   LOADCH(bC, lpC); lpC += 4 * chstep;
            PROCCH(bD, opA + 3 * chstep);   LOADCH(bD, lpD); lpD += 4 * chstep;
            opA += 4 * chstep;
        }
        // epilogue: last 4 chunks, already loaded
        PROCCH(bA, opA);
        PROCCH(bB, opA + chstep);
        PROCCH(bC, opA + 2 * chstep);
        PROCCH(bD, opA + 3 * chstep);
#undef LOADCH
#undef PROCCH
    } else {
        // generic fallback (not taken for T=2048)
        for (int t = 0; t < T; ++t) {
            double rd = (double)fmaxf(xp[(size_t)t * stride], 0.0f) * 0.001;
            s = s + rd;
            double c = v0d + s;
            double f = floor(c);
            float f32f = (float)f;
            op[(size_t)t * stride] = (f32f - fprev32) * 1000.0f;
            fprev32 = f32f;
        }
    }
}

extern "C" void kernel_launch(void* const* d_in, const int* in_sizes, int n_in,
                              void* d_out, int out_size, void* d_ws, size_t ws_size,
                              hipStream_t stream) {
    const float* x  = (const float*)d_in[0];
    const float* v0 = (const float*)d_in[1];
    float* out = (float*)d_out;

    const int U = 512;                    // fixed by the problem
    const int total = in_sizes[1];        // B*U = 16384
    const int T = in_sizes[0] / total;    // 2048

    const int block = 64;                 // 1 wave/block -> 256 blocks ~= 1/CU
    const int grid = (total + block - 1) / block;
    sdiaf_f64_kernel<<<grid, block, 0, stream>>>(x, v0, out, T, U, total);
}

// Round 6
// 245.573 us; speedup vs baseline: 1.0624x; 1.0624x over previous
//
#include <hip/hip_runtime.h>

// Sigma-delta integrate-and-fire vs a float64 numpy reference.
// Round-3 (serial per-(b,u) f64 fold, 1 wave/CU) PASSED absmax=0.0 at 90us,
// latency-bound (VALUBusy 10%, HBM 28%, Occupancy 2.7%). Fix: split T into
// G=16 groups -> 262144 threads = 4096 waves = 16/CU.
//
// Pass 1 (k1): thread (b,g,u) computes S[b][g][u] = serial f64 fold of
//   rd_i = fl64((f64)relu(x_i) * 0.001) over its L=128-element group.
// Pass 2 (k2): thread (b,g,u) folds S[b][0..g-1][u] into prefix (serial f64,
//   single pass), derives fprev bit-exactly as thread g-1's last floor,
//   re-reads its 128 x elements (L3-resident after k1; NT out-stores don't
//   evict them), recomputes the in-group fold (bit-identical to k1's),
//   floors, stores (f - fprev)*1000.
//
// Boundary exactness: fprev_g = floor(fl(fl(v0+P_{g-1})+S_{g-1})) is the
// same expression thread g-1 evaluates for its last cum. base_g =
// fl(v0 + fl(P_{g-1}+S_{g-1})) = fl(v0 + P_g) with the same fold order every
// other thread uses. Only deviation from the monolithic f64 fold is prefix
// regrouping (~1e-13 abs) vs ~1.5e-8 min cum-to-integer distance over 33.5M
// samples -> flip probability ~1e-5 per run. f32 casts of floors are exact
// (small integers); n*1000.0f vs ref n/0.001(f64) differs ~1e-10 << tol 20.

#define GROUPS 16

__global__ __launch_bounds__(256, 4)
void sdiaf_k1_sums(const float* __restrict__ x,
                   double* __restrict__ S,
                   int T, int U, int totalG /* = B*G*U */) {
#pragma clang fp contract(off)
    const int flat = blockIdx.x * blockDim.x + threadIdx.x;  // ((b*G)+g)*U + u
    if (flat >= totalG) return;
    const int u = flat % U;
    const int bg = flat / U;
    const int g = bg % GROUPS;
    const int b = bg / GROUPS;
    const int L = T / GROUPS;

    const float* __restrict__ xp =
        x + ((size_t)b * T + (size_t)g * L) * (size_t)U + (size_t)u;

    double s = 0.0;
#pragma unroll 8
    for (int i = 0; i < L; ++i) {
        double rd = (double)fmaxf(xp[(size_t)i * U], 0.0f) * 0.001;
        s = s + rd;                       // serial f64 fold (order matters)
    }
    S[flat] = s;
}

__global__ __launch_bounds__(256, 4)
void sdiaf_k2_emit(const float* __restrict__ x,
                   const float* __restrict__ v0,
                   const double* __restrict__ S,
                   float* __restrict__ out,
                   int T, int U, int totalG) {
#pragma clang fp contract(off)
    const int flat = blockIdx.x * blockDim.x + threadIdx.x;
    if (flat >= totalG) return;
    const int u = flat % U;
    const int bg = flat / U;
    const int g = bg % GROUPS;   // wave-uniform (U % 64 == 0)
    const int b = bg / GROUPS;
    const int L = T / GROUPS;

    const double v0d = (double)v0[(size_t)b * U + u];
    const double* __restrict__ Sp =
        S + ((size_t)b * GROUPS) * (size_t)U + (size_t)u;

    double base, fprev;
    if (g == 0) {
        base = v0d;
        fprev = floor(v0d);
    } else {
        // Single pass over the prefix: P = fold(S_0..S_{g-2}), then S_{g-1}.
        double P = 0.0;
        for (int j = 0; j < g - 1; ++j)
            P = P + Sp[(size_t)j * U];    // serial f64, wave-uniform trips
        const double Slast = Sp[(size_t)(g - 1) * U];
        fprev = floor((v0d + P) + Slast); // == thread g-1's last floor, bit-exact
        base  = v0d + (P + Slast);        // == fl(v0 + P_g), canonical fold order
    }

    float fprev32 = (float)fprev;         // small integer, exact

    const size_t off0 = ((size_t)b * T + (size_t)g * L) * (size_t)U + (size_t)u;
    const float* __restrict__ xp = x + off0;
    float* __restrict__ op = out + off0;

    double s = 0.0;
#pragma unroll 8
    for (int i = 0; i < L; ++i) {
        double rd = (double)fmaxf(xp[(size_t)i * U], 0.0f) * 0.001;
        s = s + rd;                       // bit-identical to k1's fold
        double c = base + s;
        double f = floor(c);
        float f32f = (float)f;
        __builtin_nontemporal_store((f32f - fprev32) * 1000.0f,
                                    &op[(size_t)i * U]);
        fprev32 = f32f;
    }
}

// Known-good round-3 fallback (serial per-(b,u) f64 fold), used only if the
// workspace is too small or T isn't divisible by GROUPS.
__global__ __launch_bounds__(64, 1)
void sdiaf_serial_f64(const float* __restrict__ x,
                      const float* __restrict__ v0,
                      float* __restrict__ out,
                      int T, int U, int total) {
#pragma clang fp contract(off)
    const int idx = blockIdx.x * blockDim.x + threadIdx.x;
    if (idx >= total) return;
    const int b = idx / U;
    const int u = idx - b * U;
    const double v0d = (double)v0[idx];
    float fprev32 = (float)floor(v0d);
    double s = 0.0;
    const size_t base = (size_t)b * (size_t)T * (size_t)U + (size_t)u;
    const float* xp = x + base;
    float* op = out + base;
#pragma unroll 8
    for (int t = 0; t < T; ++t) {
        double rd = (double)fmaxf(xp[(size_t)t * U], 0.0f) * 0.001;
        s = s + rd;
        double c = v0d + s;
        double f = floor(c);
        float f32f = (float)f;
        op[(size_t)t * U] = (f32f - fprev32) * 1000.0f;
        fprev32 = f32f;
    }
}

extern "C" void kernel_launch(void* const* d_in, const int* in_sizes, int n_in,
                              void* d_out, int out_size, void* d_ws, size_t ws_size,
                              hipStream_t stream) {
    const float* x  = (const float*)d_in[0];
    const float* v0 = (const float*)d_in[1];
    float* out = (float*)d_out;

    const int U = 512;                    // fixed by the problem
    const int total = in_sizes[1];        // B*U = 16384
    const int T = in_sizes[0] / total;    // 2048

    const size_t ws_needed = (size_t)total * GROUPS * sizeof(double);  // 2 MB

    if ((T % GROUPS) == 0 && ws_size >= ws_needed) {
        double* S = (double*)d_ws;
        const int totalG = total * GROUPS;           // 262144
        const int block = 256;
        const int grid = (totalG + block - 1) / block;
        sdiaf_k1_sums<<<grid, block, 0, stream>>>(x, S, T, U, totalG);
        sdiaf_k2_emit<<<grid, block, 0, stream>>>(x, v0, S, out, T, U, totalG);
    } else {
        const int block = 64;
        const int grid = (total + block - 1) / block;
        sdiaf_serial_f64<<<grid, block, 0, stream>>>(x, v0, out, T, U, total);
    }
}